// Round 7
// baseline (524.400 us; speedup 1.0000x reference)
//
#include <hip/hip_runtime.h>

typedef __attribute__((ext_vector_type(2))) _Float16 half2_t;

#define NJ 7
#define HID 4

// ---- ws layout (u32 slots) ----
// [0..47]    WIHJ: 12 gates x 4 half2 (pre-scaled: g<8 by -log2e, g>=8 by 2*log2e)
// [48..71]   WHHJ: 12 gates x 2 half2 (same scaling)
// [72..95]   WIHM: 12 x 2 half2
// [96..119]  WHHM: 12 x 2 half2
// [120..127] BSUMJ rz: 8 f32   ((bih+bhh)*-log2e)
// [128..131] BIHJ_n: 4 f32     (*2log2e)
// [132..135] BHHJ_n: 4 f32     (*2log2e)
// [136..143] BSUMM rz: 8 f32
// [144..147] BIHM_n: 4 f32
// [148..151] BHHM_n: 4 f32

__device__ __forceinline__ half2_t h2(unsigned int u) {
    return __builtin_bit_cast(half2_t, u);
}
__device__ __forceinline__ float fdot2f(half2_t a, half2_t b, float c) {
#if __has_builtin(__builtin_amdgcn_fdot2)
    return __builtin_amdgcn_fdot2(a, b, c, false);
#else
    return c + (float)a.x * (float)b.x + (float)a.y * (float)b.y;
#endif
}
__device__ __forceinline__ half2_t pk(float a, float b) {
    return __builtin_bit_cast(half2_t, __builtin_amdgcn_cvt_pkrtz(a, b));
}

__global__ __launch_bounds__(256) void prep_kernel(
    const float* __restrict__ Wih_j, const float* __restrict__ Whh_j,
    const float* __restrict__ bih_j, const float* __restrict__ bhh_j,
    const float* __restrict__ Wih_m, const float* __restrict__ Whh_m,
    const float* __restrict__ bih_m, const float* __restrict__ bhh_m,
    unsigned int* __restrict__ ws)
{
    const float c1 = -1.44269504f;  // -log2(e): r,z gates
    const float c2 = 2.88539008f;   // 2*log2(e): n gates
    int t = threadIdx.x;
    if (t < 48) {                       // WIHJ
        int g = t >> 2, k = t & 3;
        float s = (g < 8) ? c1 : c2;
        ws[t] = __builtin_bit_cast(unsigned int,
                    pk(Wih_j[g*8 + 2*k] * s, Wih_j[g*8 + 2*k + 1] * s));
    } else if (t < 72) {                // WHHJ
        int i = t - 48; int g = i >> 1, k = i & 1;
        float s = (g < 8) ? c1 : c2;
        ws[t] = __builtin_bit_cast(unsigned int,
                    pk(Whh_j[g*4 + 2*k] * s, Whh_j[g*4 + 2*k + 1] * s));
    } else if (t < 96) {                // WIHM
        int i = t - 72; int g = i >> 1, k = i & 1;
        float s = (g < 8) ? c1 : c2;
        ws[t] = __builtin_bit_cast(unsigned int,
                    pk(Wih_m[g*4 + 2*k] * s, Wih_m[g*4 + 2*k + 1] * s));
    } else if (t < 120) {               // WHHM
        int i = t - 96; int g = i >> 1, k = i & 1;
        float s = (g < 8) ? c1 : c2;
        ws[t] = __builtin_bit_cast(unsigned int,
                    pk(Whh_m[g*4 + 2*k] * s, Whh_m[g*4 + 2*k + 1] * s));
    } else if (t < 128) {               // BSUMJ rz
        int g = t - 120;
        ws[t] = __float_as_uint((bih_j[g] + bhh_j[g]) * c1);
    } else if (t < 132) {               // BIHJ_n
        int i = t - 128;
        ws[t] = __float_as_uint(bih_j[8 + i] * c2);
    } else if (t < 136) {               // BHHJ_n
        int i = t - 132;
        ws[t] = __float_as_uint(bhh_j[8 + i] * c2);
    } else if (t < 144) {               // BSUMM rz
        int g = t - 136;
        ws[t] = __float_as_uint((bih_m[g] + bhh_m[g]) * c1);
    } else if (t < 148) {               // BIHM_n
        int i = t - 144;
        ws[t] = __float_as_uint(bih_m[8 + i] * c2);
    } else if (t < 152) {               // BHHM_n
        int i = t - 148;
        ws[t] = __float_as_uint(bhh_m[8 + i] * c2);
    }
}

// 2 rows per thread: amortizes per-iteration uniform weight staging (s_load /
// v_mov refresh of the 152-word uniform set, which exceeds free SGPRs) across
// two independent dot-streams, and doubles per-wave ILP.
__global__ __launch_bounds__(256, 3) void aggreg_kernel(
    const float* __restrict__ x,
    const float* __restrict__ Wj,   const float* __restrict__ bj,
    const float* __restrict__ Wm,   const float* __restrict__ bm,
    const float* __restrict__ Wact, const float* __restrict__ bact,
    const unsigned int* __restrict__ wu,
    float* __restrict__ out, int B)
{
    int tid = blockIdx.x * blockDim.x + threadIdx.x;
    int row0 = tid * 2;
    if (row0 >= B) return;                 // B is even; row0+1 valid

    // ---- load both rows' x ----
    float xr[2][19];
    #pragma unroll
    for (int rr = 0; rr < 2; ++rr) {
        const float* xp = x + (size_t)(row0 + rr) * 19;
        float4 v0 = *(const float4*)(xp + 0);
        float4 v1 = *(const float4*)(xp + 4);
        float4 v2 = *(const float4*)(xp + 8);
        float4 v3 = *(const float4*)(xp + 12);
        xr[rr][0]=v0.x; xr[rr][1]=v0.y; xr[rr][2]=v0.z; xr[rr][3]=v0.w;
        xr[rr][4]=v1.x; xr[rr][5]=v1.y; xr[rr][6]=v1.z; xr[rr][7]=v1.w;
        xr[rr][8]=v2.x; xr[rr][9]=v2.y; xr[rr][10]=v2.z; xr[rr][11]=v2.w;
        xr[rr][12]=v3.x; xr[rr][13]=v3.y; xr[rr][14]=v3.z; xr[rr][15]=v3.w;
        xr[rr][16]=xp[16]; xr[rr][17]=xp[17]; xr[rr][18]=xp[18];
    }

    // ---- init ----
    float hj[2][NJ][HID], hm[2][HID];
    #pragma unroll
    for (int rr = 0; rr < 2; ++rr) {
        #pragma unroll
        for (int t = 0; t < NJ; ++t)
            #pragma unroll
            for (int o = 0; o < HID; ++o)
                hj[rr][t][o] = bj[o] + Wj[o*2+0]*xr[rr][5+t] + Wj[o*2+1]*xr[rr][12+t];
        #pragma unroll
        for (int o = 0; o < HID; ++o) {
            float a = bm[o];
            #pragma unroll
            for (int k = 0; k < 5; ++k) a += Wm[o*5+k]*xr[rr][k];
            hm[rr][o] = a;
        }
    }

    for (int it = 0; it < 7; ++it) {
        // snapshot OLD states packed (all cross-unit reads use these)
        half2_t hjp[2][NJ][2], hmp[2][2];
        #pragma unroll
        for (int rr = 0; rr < 2; ++rr) {
            #pragma unroll
            for (int t = 0; t < NJ; ++t) {
                hjp[rr][t][0] = pk(hj[rr][t][0], hj[rr][t][1]);
                hjp[rr][t][1] = pk(hj[rr][t][2], hj[rr][t][3]);
            }
            hmp[rr][0] = pk(hm[rr][0], hm[rr][1]);
            hmp[rr][1] = pk(hm[rr][2], hm[rr][3]);
        }

        // ---- m-GRU (both rows share each staged weight) ----
        float mrz[2][8];
        #pragma unroll
        for (int g = 0; g < 8; ++g) {
            unsigned w0 = wu[72 + g*2 + 0], w1 = wu[72 + g*2 + 1];
            unsigned u0 = wu[96 + g*2 + 0], u1 = wu[96 + g*2 + 1];
            float bs = __uint_as_float(wu[136 + g]);
            #pragma unroll
            for (int rr = 0; rr < 2; ++rr) {
                float a = bs;
                a = fdot2f(h2(w0), hjp[rr][0][0], a);
                a = fdot2f(h2(w1), hjp[rr][0][1], a);
                a = fdot2f(h2(u0), hmp[rr][0], a);
                a = fdot2f(h2(u1), hmp[rr][1], a);
                mrz[rr][g] = a;
            }
        }
        #pragma unroll
        for (int i = 0; i < 4; ++i) {
            int gn = 8 + i;
            unsigned w0 = wu[72 + gn*2 + 0], w1 = wu[72 + gn*2 + 1];
            unsigned u0 = wu[96 + gn*2 + 0], u1 = wu[96 + gn*2 + 1];
            float bi = __uint_as_float(wu[144 + i]);
            float bh = __uint_as_float(wu[148 + i]);
            #pragma unroll
            for (int rr = 0; rr < 2; ++rr) {
                float gi = bi;
                gi = fdot2f(h2(w0), hjp[rr][0][0], gi);
                gi = fdot2f(h2(w1), hjp[rr][0][1], gi);
                float gh = bh;
                gh = fdot2f(h2(u0), hmp[rr][0], gh);
                gh = fdot2f(h2(u1), hmp[rr][1], gh);
                float r = __builtin_amdgcn_rcpf(1.0f + __builtin_amdgcn_exp2f(mrz[rr][i]));
                float z = __builtin_amdgcn_rcpf(1.0f + __builtin_amdgcn_exp2f(mrz[rr][4+i]));
                float v = gi + r * gh;
                float n = 1.0f - 2.0f * __builtin_amdgcn_rcpf(__builtin_amdgcn_exp2f(v) + 1.0f);
                hm[rr][i] = n + z * (hm[rr][i] - n);   // in-place: joints read hmp (old)
            }
        }

        // ---- joint GRUs ----
        #pragma unroll
        for (int t = 0; t < NJ; ++t) {
            float rz[2][8];
            #pragma unroll
            for (int g = 0; g < 8; ++g) {
                unsigned a0 = wu[g*4 + 0], a1 = wu[g*4 + 1];
                unsigned a2 = wu[g*4 + 2], a3 = wu[g*4 + 3];
                unsigned s0 = wu[48 + g*2 + 0], s1 = wu[48 + g*2 + 1];
                float bs = __uint_as_float(wu[120 + g]);
                #pragma unroll
                for (int rr = 0; rr < 2; ++rr) {
                    half2_t in0 = (t == 0) ? hmp[rr][0] : hjp[rr][t-1][0];
                    half2_t in1 = (t == 0) ? hmp[rr][1] : hjp[rr][t-1][1];
                    float a = bs;
                    a = fdot2f(h2(a0), in0, a);
                    a = fdot2f(h2(a1), in1, a);
                    if (t < 6) {
                        a = fdot2f(h2(a2), hjp[rr][t+1][0], a);
                        a = fdot2f(h2(a3), hjp[rr][t+1][1], a);
                    }
                    a = fdot2f(h2(s0), hjp[rr][t][0], a);
                    a = fdot2f(h2(s1), hjp[rr][t][1], a);
                    rz[rr][g] = a;
                }
            }
            #pragma unroll
            for (int i = 0; i < 4; ++i) {
                int gn = 8 + i;
                unsigned a0 = wu[gn*4 + 0], a1 = wu[gn*4 + 1];
                unsigned a2 = wu[gn*4 + 2], a3 = wu[gn*4 + 3];
                unsigned s0 = wu[48 + gn*2 + 0], s1 = wu[48 + gn*2 + 1];
                float bi = __uint_as_float(wu[128 + i]);
                float bh = __uint_as_float(wu[132 + i]);
                #pragma unroll
                for (int rr = 0; rr < 2; ++rr) {
                    half2_t in0 = (t == 0) ? hmp[rr][0] : hjp[rr][t-1][0];
                    half2_t in1 = (t == 0) ? hmp[rr][1] : hjp[rr][t-1][1];
                    float gi = bi;
                    gi = fdot2f(h2(a0), in0, gi);
                    gi = fdot2f(h2(a1), in1, gi);
                    if (t < 6) {
                        gi = fdot2f(h2(a2), hjp[rr][t+1][0], gi);
                        gi = fdot2f(h2(a3), hjp[rr][t+1][1], gi);
                    }
                    float gh = bh;
                    gh = fdot2f(h2(s0), hjp[rr][t][0], gh);
                    gh = fdot2f(h2(s1), hjp[rr][t][1], gh);
                    float r = __builtin_amdgcn_rcpf(1.0f + __builtin_amdgcn_exp2f(rz[rr][i]));
                    float z = __builtin_amdgcn_rcpf(1.0f + __builtin_amdgcn_exp2f(rz[rr][4+i]));
                    float v = gi + r * gh;
                    float n = 1.0f - 2.0f * __builtin_amdgcn_rcpf(__builtin_amdgcn_exp2f(v) + 1.0f);
                    hj[rr][t][i] = n + z * (hj[rr][t][i] - n);  // in-place: peers read hjp
                }
            }
        }
    }

    // ---- output: 14 contiguous floats per thread ----
    const float wa0 = Wact[0], wa1 = Wact[1], wa2 = Wact[2], wa3 = Wact[3];
    const float ba = bact[0];
    float* op = out + (size_t)row0 * 7;
    #pragma unroll
    for (int rr = 0; rr < 2; ++rr)
        #pragma unroll
        for (int t = 0; t < NJ; ++t)
            op[rr*7 + t] = ba + wa0*hj[rr][t][0] + wa1*hj[rr][t][1]
                              + wa2*hj[rr][t][2] + wa3*hj[rr][t][3];
}

extern "C" void kernel_launch(void* const* d_in, const int* in_sizes, int n_in,
                              void* d_out, int out_size, void* d_ws, size_t ws_size,
                              hipStream_t stream) {
    const float* x      = (const float*)d_in[0];
    const float* Wj     = (const float*)d_in[1];
    const float* bj     = (const float*)d_in[2];
    const float* Wm     = (const float*)d_in[3];
    const float* bm     = (const float*)d_in[4];
    const float* Wih_j  = (const float*)d_in[5];
    const float* Whh_j  = (const float*)d_in[6];
    const float* bih_j  = (const float*)d_in[7];
    const float* bhh_j  = (const float*)d_in[8];
    const float* Wih_m  = (const float*)d_in[9];
    const float* Whh_m  = (const float*)d_in[10];
    const float* bih_m  = (const float*)d_in[11];
    const float* bhh_m  = (const float*)d_in[12];
    const float* Wact   = (const float*)d_in[13];
    const float* bact   = (const float*)d_in[14];
    float* out = (float*)d_out;
    unsigned int* ws = (unsigned int*)d_ws;

    prep_kernel<<<1, 256, 0, stream>>>(Wih_j, Whh_j, bih_j, bhh_j,
                                       Wih_m, Whh_m, bih_m, bhh_m, ws);

    int B = in_sizes[0] / 19;                       // 2097152 (even)
    int threads_needed = B / 2;
    const int block = 256;
    const int grid = (threads_needed + block - 1) / block;
    aggreg_kernel<<<grid, block, 0, stream>>>(
        x, Wj, bj, Wm, bm, Wact, bact, ws, out, B);
}